// Round 10
// baseline (415.222 us; speedup 1.0000x reference)
//
#include <hip/hip_runtime.h>
#include <hip/hip_bf16.h>
#include <stdint.h>

#define NPROT 19000
#define NDRUG 4000
#define NCELL 16
#define BATCH 4096
#define NEDGE 40000
#define L0 2048
#define L1DIM 1024
#define INDIM 38032
#define HALFDIM 19016
#define WSTN 19008   // protein slots: 19000 + 8 pad (dummy at 19000)

typedef float f32x4 __attribute__((ext_vector_type(4)));
typedef short s16x8 __attribute__((ext_vector_type(8)));

// fused: LDS histogram -> exclusive scan (dptr) -> scatter to CSR-by-drug
__global__ __launch_bounds__(256) void edges_kernel(const int* __restrict__ drug,
                                                    const int* __restrict__ prot,
                                                    int* __restrict__ dptr,
                                                    int* __restrict__ dtmp) {
    __shared__ int h[NDRUG];
    __shared__ int basec[NDRUG];
    __shared__ int part[256];
    int t = threadIdx.x;
    for (int i = t; i < NDRUG; i += 256) h[i] = 0;
    __syncthreads();
    for (int e = t; e < NEDGE; e += 256) atomicAdd(&h[drug[e]], 1);
    __syncthreads();
    int s = 0;
#pragma unroll
    for (int j = 0; j < 16; ++j) {
        int idx = t * 16 + j;
        if (idx < NDRUG) s += h[idx];
    }
    part[t] = s;
    __syncthreads();
    if (t == 0) {
        int run = 0;
        for (int i = 0; i < 256; ++i) { int v = part[i]; part[i] = run; run += v; }
    }
    __syncthreads();
    int run = part[t];
#pragma unroll
    for (int j = 0; j < 16; ++j) {
        int idx = t * 16 + j;
        if (idx < NDRUG) { basec[idx] = run; dptr[idx] = run; run += h[idx]; }
    }
    if (t == 255) dptr[NDRUG] = NEDGE;
    __syncthreads();
    for (int i = t; i < NDRUG; i += 256) h[i] = 0;
    __syncthreads();
    for (int e = t; e < NEDGE; e += 256) {
        int d = drug[e];
        int pos = basec[d] + atomicAdd(&h[d], 1);
        dtmp[pos] = prot[e];
    }
}

// per-drug: insertion-sort protein list, dedup (reference .set(1.0) semantics)
__global__ void sortdedup_kernel(const int* __restrict__ dptr, int* __restrict__ dtmp,
                                 int* __restrict__ dcnt) {
    int d = blockIdx.x * 256 + threadIdx.x;
    if (d >= NDRUG) return;
    int beg = dptr[d], end = dptr[d + 1];
    for (int i = beg + 1; i < end; ++i) {
        int v = dtmp[i];
        int j = i - 1;
        while (j >= beg && dtmp[j] > v) { dtmp[j + 1] = dtmp[j]; --j; }
        dtmp[j + 1] = v;
    }
    int c = 0, prev = -1;
    for (int i = beg; i < end; ++i) {
        int v = dtmp[i];
        if (v != prev) { dtmp[beg + c] = v; ++c; prev = v; }
    }
    dcnt[d] = c;
}

// per-slot (512 threads) prefix of entry counts over the 8 owned drugs;
// wlen[w] = max over 64 lanes of total; wbase = running base
__global__ __launch_bounds__(512) void stream_meta_kernel(const int* __restrict__ dcnt,
                                                          int* __restrict__ wlen,
                                                          int* __restrict__ wbase,
                                                          int* __restrict__ pref,
                                                          int* __restrict__ tcnt) {
    __shared__ int wl[8];
    int t = threadIdx.x;
    if (t < 8) wl[t] = 0;
    __syncthreads();
    int c = 0;
#pragma unroll
    for (int k = 0; k < 8; ++k) {
        int d = t + (k << 9);
        pref[t * 8 + k] = c;
        if (d < NDRUG) c += max(dcnt[d], 1);
    }
    tcnt[t] = c;
    atomicMax(&wl[t >> 6], c);
    __syncthreads();
    if (t == 0) {
        int run = 0;
        for (int w = 0; w < 8; ++w) {
            wlen[w] = wl[w];
            wbase[w] = run;
            run += wl[w] * 64;
        }
    }
}

// drug-parallel fill of the wave-interleaved u16 stream.
// entry = p | (last<<15); slot t's i-th entry at wbase[t>>6] + (t&63) + i*64.
__global__ __launch_bounds__(256) void fill_stream_kernel(const int* __restrict__ dptr,
                                                          const int* __restrict__ dcnt,
                                                          const int* __restrict__ dtmp,
                                                          const int* __restrict__ wbase,
                                                          const int* __restrict__ wlen,
                                                          const int* __restrict__ pref,
                                                          const int* __restrict__ tcnt,
                                                          unsigned short* __restrict__ estream) {
    int g = blockIdx.x * 256 + threadIdx.x;
    if (g < NDRUG) {
        int d = g;
        int t = d & 511, k = d >> 9;
        int base = wbase[t >> 6] + (t & 63);
        int idx = pref[t * 8 + k];
        int n = dcnt[d], b = dptr[d];
        if (n == 0) {
            estream[base + idx * 64] = (unsigned short)(19000 | 0x8000);
        } else {
            for (int i = 0; i < n; ++i) {
                unsigned short e = (unsigned short)dtmp[b + i];
                if (i == n - 1) e |= 0x8000;
                estream[base + (idx + i) * 64] = e;
            }
        }
    } else if (g < NDRUG + 512) {
        int t = g - NDRUG;
        int base = wbase[t >> 6] + (t & 63);
        int wl = wlen[t >> 6];
        for (int idx = tcnt[t]; idx < wl; ++idx)
            estream[base + idx * 64] = (unsigned short)19000;
    }
}

// BASE[c][ch] = b0[ch] + W0[ch, 19000+c] + W0[ch, 38016+c]
__global__ void base_kernel(const float* __restrict__ W0, const float* __restrict__ b0,
                            float* __restrict__ BASE) {
    int i = blockIdx.x * 256 + threadIdx.x;
    if (i < NCELL * L0) {
        int c = i >> 11, ch = i & 2047;
        const float* wr = W0 + (size_t)ch * INDIM;
        BASE[(size_t)c * L0 + ch] = b0[ch] + wr[NPROT + c] + wr[HALFDIM + NPROT + c];
    }
}

// RNE f32->bf16 pair pack: low16 = a, high16 = b
__device__ inline unsigned bfpair(float a, float b) {
    unsigned ua = __float_as_uint(a), ub = __float_as_uint(b);
    ua += 0x7fffu + ((ua >> 16) & 1u);
    ub += 0x7fffu + ((ub >> 16) & 1u);
    return (ua >> 16) | (ub & 0xffff0000u);
}

// Register-accumulator drug sum, 4 channels/block as 2 packed-bf16 dwords.
__global__ __launch_bounds__(512) void drug_sum_kernel(const float* __restrict__ W0,
                                                       const unsigned short* __restrict__ estream,
                                                       const int* __restrict__ wbase,
                                                       const int* __restrict__ wlen,
                                                       float* __restrict__ SA,
                                                       float* __restrict__ SB) {
    __shared__ uint2 wst[WSTN];  // 152064 B
    int t = threadIdx.x;
    int bid = blockIdx.x;        // 1024 blocks
    int j = bid & 7;
    int k2 = bid >> 3;           // 0..127
    int ch4 = k2 & 3;
    int ghi = k2 >> 2;           // 0..31
    int group = j + 8 * ghi;     // 0..255
    int hb = group >> 7;
    int line = group & 127;
    int ch0 = line * 16 + ch4 * 4;
    size_t colbase = (size_t)hb * HALFDIM;

    const float* sA = W0 + (size_t)(ch0 + 0) * INDIM + colbase;
    const float* sB = W0 + (size_t)(ch0 + 1) * INDIM + colbase;
    const float* sC = W0 + (size_t)(ch0 + 2) * INDIM + colbase;
    const float* sD = W0 + (size_t)(ch0 + 3) * INDIM + colbase;
    for (int i = t * 4; i < 19000; i += 2048) {
        float4 a = *(const float4*)(sA + i);
        float4 b = *(const float4*)(sB + i);
        float4 c = *(const float4*)(sC + i);
        float4 d = *(const float4*)(sD + i);
        uint4 q0, q1;
        q0.x = bfpair(a.x, b.x); q0.y = bfpair(c.x, d.x);
        q0.z = bfpair(a.y, b.y); q0.w = bfpair(c.y, d.y);
        q1.x = bfpair(a.z, b.z); q1.y = bfpair(c.z, d.z);
        q1.z = bfpair(a.w, b.w); q1.w = bfpair(c.w, d.w);
        *(uint4*)&wst[i] = q0;
        *(uint4*)&wst[i + 2] = q1;
    }
    if (t < 8) { wst[19000 + t].x = 0u; wst[19000 + t].y = 0u; }
    int wv = t >> 6;
    int base = wbase[wv] + (t & 63);
    int wl = wlen[wv];
    __syncthreads();

    float x0 = 0.f, x1 = 0.f, x2 = 0.f, x3 = 0.f;
    int kk = 0;
    float* dst = (hb ? SB : SA) + ch0;

    int nfull = wl >> 3, rem = wl & 7;
    unsigned e[8];

    auto process = [&](const unsigned* ev) {
#pragma unroll
        for (int k = 0; k < 8; ++k) {
            uint2 w = wst[ev[k] & 0x7fffu];
            x0 += __uint_as_float(w.x << 16);
            x1 += __uint_as_float(w.x & 0xffff0000u);
            x2 += __uint_as_float(w.y << 16);
            x3 += __uint_as_float(w.y & 0xffff0000u);
            if (ev[k] & 0x8000u) {
                float4 v;
                v.x = x0; v.y = x1; v.z = x2; v.w = x3;
                *(float4*)&dst[(size_t)(t + (kk << 9)) * L0] = v;
                ++kk; x0 = 0.f; x1 = 0.f; x2 = 0.f; x3 = 0.f;
            }
        }
    };

    if (nfull > 0) {
#pragma unroll
        for (int k = 0; k < 8; ++k) e[k] = estream[base + k * 64];
        base += 512;
        for (int it = 1; it < nfull; ++it) {
            unsigned f[8];
#pragma unroll
            for (int k = 0; k < 8; ++k) f[k] = estream[base + k * 64];
            base += 512;
            process(e);
#pragma unroll
            for (int k = 0; k < 8; ++k) e[k] = f[k];
        }
        process(e);
    }
    for (int k = 0; k < rem; ++k) {
        unsigned ev = estream[base + k * 64];
        uint2 w = wst[ev & 0x7fffu];
        x0 += __uint_as_float(w.x << 16);
        x1 += __uint_as_float(w.x & 0xffff0000u);
        x2 += __uint_as_float(w.y << 16);
        x3 += __uint_as_float(w.y & 0xffff0000u);
        if (ev & 0x8000u) {
            float4 v;
            v.x = x0; v.y = x1; v.z = x2; v.w = x3;
            *(float4*)&dst[(size_t)(t + (kk << 9)) * L0] = v;
            ++kk; x0 = 0.f; x1 = 0.f; x2 = 0.f; x3 = 0.f;
        }
    }
}

__global__ void cvtw1_kernel(const float* __restrict__ W1, __hip_bfloat16* __restrict__ W1b) {
    int i = blockIdx.x * 256 + threadIdx.x;  // one float4 each
    const int n = L1DIM * L0 / 4;
    if (i < n) {
        float4 v = ((const float4*)W1)[i];
        union { ushort4 u; __hip_bfloat16 h[4]; } pk;
        pk.h[0] = __float2bfloat16(v.x);
        pk.h[1] = __float2bfloat16(v.y);
        pk.h[2] = __float2bfloat16(v.z);
        pk.h[3] = __float2bfloat16(v.w);
        ((ushort4*)W1b)[i] = pk.u;
    }
}

// h1[b]      = relu(BASE[c] + SA[d1] + SB[d2])  (x1)
// h1[4096+b] = relu(BASE[c] + SA[d2] + SB[d1])  (x2)
__global__ __launch_bounds__(256) void build_h_kernel(const int* __restrict__ dp,
                                                      const int* __restrict__ cl,
                                                      const float* __restrict__ SA,
                                                      const float* __restrict__ SB,
                                                      const float* __restrict__ BASE,
                                                      __hip_bfloat16* __restrict__ h1) {
    int b = blockIdx.x;
    int d1 = dp[2 * b], d2 = dp[2 * b + 1], c = cl[b];
    const float* bs = BASE + (size_t)c * L0;
    const float* a1 = SA + (size_t)d1 * L0;
    const float* a2 = SA + (size_t)d2 * L0;
    const float* s1 = SB + (size_t)d1 * L0;
    const float* s2 = SB + (size_t)d2 * L0;
    for (int ch = threadIdx.x * 4; ch < L0; ch += 1024) {
        float4 vb = *(const float4*)(bs + ch);
        float4 va1 = *(const float4*)(a1 + ch);
        float4 va2 = *(const float4*)(a2 + ch);
        float4 vs1 = *(const float4*)(s1 + ch);
        float4 vs2 = *(const float4*)(s2 + ch);
        union { ushort4 u; __hip_bfloat16 h[4]; } p1, p2;
        const float* fb = (const float*)&vb;
        const float* fa1 = (const float*)&va1;
        const float* fa2 = (const float*)&va2;
        const float* fs1 = (const float*)&vs1;
        const float* fs2 = (const float*)&vs2;
#pragma unroll
        for (int j = 0; j < 4; ++j) {
            float z1 = fb[j] + fa1[j] + fs2[j];
            float z2 = fb[j] + fa2[j] + fs1[j];
            p1.h[j] = __float2bfloat16(fmaxf(z1, 0.f));
            p2.h[j] = __float2bfloat16(fmaxf(z2, 0.f));
        }
        *(ushort4*)((__hip_bfloat16*)h1 + (size_t)b * L0 + ch) = p1.u;
        *(ushort4*)((__hip_bfloat16*)h1 + (size_t)(BATCH + b) * L0 + ch) = p2.u;
    }
}

// out[i] = b2 (init for fused atomic layer-2)
__global__ void init_out_kernel(float* __restrict__ out, const float* __restrict__ b2, int n) {
    int i = blockIdx.x * 256 + threadIdx.x;
    if (i < n) out[i] = b2[0];
}

// Fused layers 1+2: C = relu(A @ W1b^T + b1); out += C @ W2  (atomic per row)
// BKK=64, XOR-swizzled LDS (pre-swizzled global source col), XCD block swizzle.
#define BM 128
#define BN 128
#define BK2 64
__global__ __launch_bounds__(256) void gemm_kernel(const __hip_bfloat16* __restrict__ A,
                                                   const __hip_bfloat16* __restrict__ B,
                                                   const float* __restrict__ bias,
                                                   const float* __restrict__ W2,
                                                   float* __restrict__ out,
                                                   int M, int N, int K) {
    __shared__ __hip_bfloat16 As[BM * BK2];
    __shared__ __hip_bfloat16 Bs[BN * BK2];
    int t = threadIdx.x;
    int bid = blockIdx.x;          // 512 blocks
    // XCD swizzle: xcd = bid&7 owns row-strips [xcd*8, xcd*8+8)
    int xcd = bid & 7, ii2 = bid >> 3;       // ii2: 0..63
    int by = xcd * 8 + (ii2 >> 3);           // 0..63
    int bx = ii2 & 7;                        // 0..7
    int brow = by * BM, bcol = bx * BN;
    int w = t >> 6, l = t & 63;
    int wr = w >> 1, wc = w & 1;
    f32x4 acc[4][4] = {};
    int row = l & 15, ko = (l >> 4) * 8;
    int swz = (row & 7) * 8;
    for (int k0 = 0; k0 < K; k0 += BK2) {
#pragma unroll
        for (int i = 0; i < 4; ++i) {
            int idx = i * 256 + t;              // 0..1023
            int r = idx >> 3;
            int cb = ((idx & 7) ^ (r & 7)) * 8; // pre-swizzled source col
            __builtin_amdgcn_global_load_lds(
                (const __attribute__((address_space(1))) void*)(A + (size_t)(brow + r) * K + k0 + cb),
                (__attribute__((address_space(3))) void*)(&As[idx * 8]), 16, 0, 0);
            __builtin_amdgcn_global_load_lds(
                (const __attribute__((address_space(1))) void*)(B + (size_t)(bcol + r) * K + k0 + cb),
                (__attribute__((address_space(3))) void*)(&Bs[idx * 8]), 16, 0, 0);
        }
        __syncthreads();
#pragma unroll
        for (int ks = 0; ks < 2; ++ks) {
            int col = (ks * 32 + ko) ^ swz;
            s16x8 af[4], bfr[4];
#pragma unroll
            for (int m = 0; m < 4; ++m)
                af[m] = *(const s16x8*)(&As[(wr * 64 + m * 16 + row) * BK2 + col]);
#pragma unroll
            for (int n = 0; n < 4; ++n)
                bfr[n] = *(const s16x8*)(&Bs[(wc * 64 + n * 16 + row) * BK2 + col]);
#pragma unroll
            for (int m = 0; m < 4; ++m)
#pragma unroll
                for (int n = 0; n < 4; ++n)
                    acc[m][n] = __builtin_amdgcn_mfma_f32_16x16x32_bf16(af[m], bfr[n], acc[m][n], 0, 0, 0);
        }
        __syncthreads();
    }
    // fused epilogue: s_row = sum_cols relu(acc + b1[col]) * W2[col]
    int cr = (l >> 4) * 4;
    int cc = l & 15;
#pragma unroll
    for (int m = 0; m < 4; ++m) {
        float s[4] = {0.f, 0.f, 0.f, 0.f};
#pragma unroll
        for (int n = 0; n < 4; ++n) {
            int gcol = bcol + wc * 64 + n * 16 + cc;
            float bv = bias[gcol];
            float wv = W2[gcol];
#pragma unroll
            for (int j = 0; j < 4; ++j) {
                float v = fmaxf(acc[m][n][j] + bv, 0.f);
                s[j] += v * wv;
            }
        }
#pragma unroll
        for (int mask = 1; mask < 16; mask <<= 1) {
#pragma unroll
            for (int j = 0; j < 4; ++j) s[j] += __shfl_xor(s[j], mask);
        }
        if (cc == 0) {
            int grow = brow + wr * 64 + m * 16 + cr;
#pragma unroll
            for (int j = 0; j < 4; ++j) atomicAdd(&out[grow + j], s[j]);
        }
    }
}

extern "C" void kernel_launch(void* const* d_in, const int* in_sizes, int n_in,
                              void* d_out, int out_size, void* d_ws, size_t ws_size,
                              hipStream_t stream) {
    const int* drug_pairs = (const int*)d_in[0];
    const int* cell_lines = (const int*)d_in[1];
    const int* dpi_drug = (const int*)d_in[2];
    const int* dpi_prot = (const int*)d_in[3];
    const float* W0 = (const float*)d_in[4];
    const float* b0 = (const float*)d_in[5];
    const float* W1 = (const float*)d_in[6];
    const float* b1 = (const float*)d_in[7];
    const float* W2 = (const float*)d_in[8];
    const float* b2 = (const float*)d_in[9];
    float* out = (float*)d_out;

    char* ws = (char*)d_ws;
    size_t off = 0;
    auto alloc = [&](size_t bytes) {
        char* p = ws + off;
        off += (bytes + 255) & ~(size_t)255;
        return p;
    };
    float* SA = (float*)alloc((size_t)NDRUG * L0 * 4);
    float* SB = (float*)alloc((size_t)NDRUG * L0 * 4);
    float* BASE = (float*)alloc((size_t)NCELL * L0 * 4);
    __hip_bfloat16* W1b = (__hip_bfloat16*)alloc((size_t)L1DIM * L0 * 2);
    __hip_bfloat16* h1 = (__hip_bfloat16*)alloc((size_t)2 * BATCH * L0 * 2);
    int* dptr = (int*)alloc((size_t)(NDRUG + 1) * 4);
    int* dtmp = (int*)alloc((size_t)NEDGE * 4);
    int* dcnt = (int*)alloc((size_t)NDRUG * 4);
    int* wlen = (int*)alloc(8 * 4);
    int* wbase = (int*)alloc(8 * 4);
    int* pref = (int*)alloc((size_t)512 * 8 * 4);
    int* tcnt = (int*)alloc((size_t)512 * 4);
    unsigned short* estream = (unsigned short*)alloc((size_t)64 * (NEDGE + NDRUG + 512) * 2);

    edges_kernel<<<1, 256, 0, stream>>>(dpi_drug, dpi_prot, dptr, dtmp);
    sortdedup_kernel<<<(NDRUG + 255) / 256, 256, 0, stream>>>(dptr, dtmp, dcnt);
    stream_meta_kernel<<<1, 512, 0, stream>>>(dcnt, wlen, wbase, pref, tcnt);
    fill_stream_kernel<<<(NDRUG + 512 + 255) / 256, 256, 0, stream>>>(dptr, dcnt, dtmp, wbase,
                                                                      wlen, pref, tcnt, estream);
    base_kernel<<<(NCELL * L0 + 255) / 256, 256, 0, stream>>>(W0, b0, BASE);
    drug_sum_kernel<<<L0 / 2, 512, 0, stream>>>(W0, estream, wbase, wlen, SA, SB);
    cvtw1_kernel<<<(L1DIM * L0 / 4 + 255) / 256, 256, 0, stream>>>(W1, W1b);
    build_h_kernel<<<BATCH, 256, 0, stream>>>(drug_pairs, cell_lines, SA, SB, BASE, h1);
    init_out_kernel<<<(2 * BATCH + 255) / 256, 256, 0, stream>>>(out, b2, 2 * BATCH);
    gemm_kernel<<<(2 * BATCH / BM) * (L1DIM / BN), 256, 0, stream>>>(h1, W1b, b1, W2, out,
                                                                     2 * BATCH, L1DIM, L0);
}

// Round 11
// 264.441 us; speedup vs baseline: 1.5702x; 1.5702x over previous
//
#include <hip/hip_runtime.h>
#include <hip/hip_bf16.h>
#include <stdint.h>

#define NPROT 19000
#define NDRUG 4000
#define NCELL 16
#define BATCH 4096
#define NEDGE 40000
#define L0 2048
#define L1DIM 1024
#define INDIM 38032
#define HALFDIM 19016
#define WSTN 19008   // protein slots: 19000 + 8 pad (dummy at 19000)

typedef float f32x4 __attribute__((ext_vector_type(4)));
typedef short s16x8 __attribute__((ext_vector_type(8)));

__global__ void zero_all_kernel(int* __restrict__ p, int n) {
    int i = blockIdx.x * 256 + threadIdx.x;
    if (i < n) p[i] = 0;
}

__global__ void hist_kernel(const int* __restrict__ drug, int* __restrict__ hist) {
    int e = blockIdx.x * 256 + threadIdx.x;
    if (e < NEDGE) atomicAdd(&hist[drug[e]], 1);
}

// generic single-block exclusive scan: row_ptr[0..n], row_ptr[n] = total
__global__ __launch_bounds__(256) void scan_kernel(const int* __restrict__ hist,
                                                   int* __restrict__ row_ptr, int n) {
    __shared__ int part[256];
    int t = threadIdx.x;
    int per = (n + 255) / 256;
    int s = 0;
    for (int j = 0; j < per; ++j) {
        int idx = t * per + j;
        if (idx < n) s += hist[idx];
    }
    part[t] = s;
    __syncthreads();
    if (t == 0) {
        int run = 0;
        for (int i = 0; i < 256; ++i) { int v = part[i]; part[i] = run; run += v; }
    }
    __syncthreads();
    int run = part[t];
    for (int j = 0; j < per; ++j) {
        int idx = t * per + j;
        if (idx < n) { row_ptr[idx] = run; run += hist[idx]; }
    }
    if (t == 255) row_ptr[n] = run;
}

// CSR by drug: dtmp[dptr[d] + k] = protein
__global__ void scatter_kernel(const int* __restrict__ drug, const int* __restrict__ prot,
                               const int* __restrict__ dptr, int* __restrict__ cnt,
                               int* __restrict__ dtmp) {
    int e = blockIdx.x * 256 + threadIdx.x;
    if (e < NEDGE) {
        int d = drug[e];
        int pos = dptr[d] + atomicAdd(&cnt[d], 1);
        dtmp[pos] = prot[e];
    }
}

// per-drug: insertion-sort protein list, dedup (reference .set(1.0) semantics)
__global__ void sortdedup_kernel(const int* __restrict__ dptr, int* __restrict__ dtmp,
                                 int* __restrict__ dcnt) {
    int d = blockIdx.x * 256 + threadIdx.x;
    if (d >= NDRUG) return;
    int beg = dptr[d], end = dptr[d + 1];
    for (int i = beg + 1; i < end; ++i) {
        int v = dtmp[i];
        int j = i - 1;
        while (j >= beg && dtmp[j] > v) { dtmp[j + 1] = dtmp[j]; --j; }
        dtmp[j + 1] = v;
    }
    int c = 0, prev = -1;
    for (int i = beg; i < end; ++i) {
        int v = dtmp[i];
        if (v != prev) { dtmp[beg + c] = v; ++c; prev = v; }
    }
    dcnt[d] = c;
}

// per-slot (512 threads) prefix of entry counts over the 8 owned drugs;
// wlen[w] = max over 64 lanes of total; wbase = running base
__global__ __launch_bounds__(512) void stream_meta_kernel(const int* __restrict__ dcnt,
                                                          int* __restrict__ wlen,
                                                          int* __restrict__ wbase,
                                                          int* __restrict__ pref,
                                                          int* __restrict__ tcnt) {
    __shared__ int wl[8];
    int t = threadIdx.x;
    if (t < 8) wl[t] = 0;
    __syncthreads();
    int c = 0;
#pragma unroll
    for (int k = 0; k < 8; ++k) {
        int d = t + (k << 9);
        pref[t * 8 + k] = c;
        if (d < NDRUG) c += max(dcnt[d], 1);
    }
    tcnt[t] = c;
    atomicMax(&wl[t >> 6], c);
    __syncthreads();
    if (t == 0) {
        int run = 0;
        for (int w = 0; w < 8; ++w) {
            wlen[w] = wl[w];
            wbase[w] = run;
            run += wl[w] * 64;
        }
    }
}

// drug-parallel fill of the wave-interleaved u16 stream.
// entry = p | (last<<15); slot t's i-th entry at wbase[t>>6] + (t&63) + i*64.
__global__ __launch_bounds__(256) void fill_stream_kernel(const int* __restrict__ dptr,
                                                          const int* __restrict__ dcnt,
                                                          const int* __restrict__ dtmp,
                                                          const int* __restrict__ wbase,
                                                          const int* __restrict__ wlen,
                                                          const int* __restrict__ pref,
                                                          const int* __restrict__ tcnt,
                                                          unsigned short* __restrict__ estream) {
    int g = blockIdx.x * 256 + threadIdx.x;
    if (g < NDRUG) {
        int d = g;
        int t = d & 511, k = d >> 9;
        int base = wbase[t >> 6] + (t & 63);
        int idx = pref[t * 8 + k];
        int n = dcnt[d], b = dptr[d];
        if (n == 0) {
            estream[base + idx * 64] = (unsigned short)(19000 | 0x8000);
        } else {
            for (int i = 0; i < n; ++i) {
                unsigned short e = (unsigned short)dtmp[b + i];
                if (i == n - 1) e |= 0x8000;
                estream[base + (idx + i) * 64] = e;
            }
        }
    } else if (g < NDRUG + 512) {
        int t = g - NDRUG;
        int base = wbase[t >> 6] + (t & 63);
        int wl = wlen[t >> 6];
        for (int idx = tcnt[t]; idx < wl; ++idx)
            estream[base + idx * 64] = (unsigned short)19000;
    }
}

// BASE[c][ch] = b0[ch] + W0[ch, 19000+c] + W0[ch, 38016+c]
__global__ void base_kernel(const float* __restrict__ W0, const float* __restrict__ b0,
                            float* __restrict__ BASE) {
    int i = blockIdx.x * 256 + threadIdx.x;
    if (i < NCELL * L0) {
        int c = i >> 11, ch = i & 2047;
        const float* wr = W0 + (size_t)ch * INDIM;
        BASE[(size_t)c * L0 + ch] = b0[ch] + wr[NPROT + c] + wr[HALFDIM + NPROT + c];
    }
}

// RNE f32->bf16 pair pack: low16 = a, high16 = b
__device__ inline unsigned bfpair(float a, float b) {
    unsigned ua = __float_as_uint(a), ub = __float_as_uint(b);
    ua += 0x7fffu + ((ua >> 16) & 1u);
    ub += 0x7fffu + ((ub >> 16) & 1u);
    return (ua >> 16) | (ub & 0xffff0000u);
}

// Register-accumulator drug sum, 4 channels/block as 2 packed-bf16 dwords.
__global__ __launch_bounds__(512) void drug_sum_kernel(const float* __restrict__ W0,
                                                       const unsigned short* __restrict__ estream,
                                                       const int* __restrict__ wbase,
                                                       const int* __restrict__ wlen,
                                                       float* __restrict__ SA,
                                                       float* __restrict__ SB) {
    __shared__ uint2 wst[WSTN];  // 152064 B
    int t = threadIdx.x;
    int bid = blockIdx.x;        // 1024 blocks
    int j = bid & 7;
    int k2 = bid >> 3;           // 0..127
    int ch4 = k2 & 3;
    int ghi = k2 >> 2;           // 0..31
    int group = j + 8 * ghi;     // 0..255
    int hb = group >> 7;
    int line = group & 127;
    int ch0 = line * 16 + ch4 * 4;
    size_t colbase = (size_t)hb * HALFDIM;

    const float* sA = W0 + (size_t)(ch0 + 0) * INDIM + colbase;
    const float* sB = W0 + (size_t)(ch0 + 1) * INDIM + colbase;
    const float* sC = W0 + (size_t)(ch0 + 2) * INDIM + colbase;
    const float* sD = W0 + (size_t)(ch0 + 3) * INDIM + colbase;
    for (int i = t * 4; i < 19000; i += 2048) {
        float4 a = *(const float4*)(sA + i);
        float4 b = *(const float4*)(sB + i);
        float4 c = *(const float4*)(sC + i);
        float4 d = *(const float4*)(sD + i);
        uint4 q0, q1;
        q0.x = bfpair(a.x, b.x); q0.y = bfpair(c.x, d.x);
        q0.z = bfpair(a.y, b.y); q0.w = bfpair(c.y, d.y);
        q1.x = bfpair(a.z, b.z); q1.y = bfpair(c.z, d.z);
        q1.z = bfpair(a.w, b.w); q1.w = bfpair(c.w, d.w);
        *(uint4*)&wst[i] = q0;
        *(uint4*)&wst[i + 2] = q1;
    }
    if (t < 8) { wst[19000 + t].x = 0u; wst[19000 + t].y = 0u; }
    int wv = t >> 6;
    int base = wbase[wv] + (t & 63);
    int wl = wlen[wv];
    __syncthreads();

    float x0 = 0.f, x1 = 0.f, x2 = 0.f, x3 = 0.f;
    int kk = 0;
    float* dst = (hb ? SB : SA) + ch0;

    int nfull = wl >> 3, rem = wl & 7;
    unsigned e[8];

    auto process = [&](const unsigned* ev) {
#pragma unroll
        for (int k = 0; k < 8; ++k) {
            uint2 w = wst[ev[k] & 0x7fffu];
            x0 += __uint_as_float(w.x << 16);
            x1 += __uint_as_float(w.x & 0xffff0000u);
            x2 += __uint_as_float(w.y << 16);
            x3 += __uint_as_float(w.y & 0xffff0000u);
            if (ev[k] & 0x8000u) {
                float4 v;
                v.x = x0; v.y = x1; v.z = x2; v.w = x3;
                *(float4*)&dst[(size_t)(t + (kk << 9)) * L0] = v;
                ++kk; x0 = 0.f; x1 = 0.f; x2 = 0.f; x3 = 0.f;
            }
        }
    };

    if (nfull > 0) {
#pragma unroll
        for (int k = 0; k < 8; ++k) e[k] = estream[base + k * 64];
        base += 512;
        for (int it = 1; it < nfull; ++it) {
            unsigned f[8];
#pragma unroll
            for (int k = 0; k < 8; ++k) f[k] = estream[base + k * 64];
            base += 512;
            process(e);
#pragma unroll
            for (int k = 0; k < 8; ++k) e[k] = f[k];
        }
        process(e);
    }
    for (int k = 0; k < rem; ++k) {
        unsigned ev = estream[base + k * 64];
        uint2 w = wst[ev & 0x7fffu];
        x0 += __uint_as_float(w.x << 16);
        x1 += __uint_as_float(w.x & 0xffff0000u);
        x2 += __uint_as_float(w.y << 16);
        x3 += __uint_as_float(w.y & 0xffff0000u);
        if (ev & 0x8000u) {
            float4 v;
            v.x = x0; v.y = x1; v.z = x2; v.w = x3;
            *(float4*)&dst[(size_t)(t + (kk << 9)) * L0] = v;
            ++kk; x0 = 0.f; x1 = 0.f; x2 = 0.f; x3 = 0.f;
        }
    }
}

__global__ void cvtw1_kernel(const float* __restrict__ W1, __hip_bfloat16* __restrict__ W1b) {
    int i = blockIdx.x * 256 + threadIdx.x;  // one float4 each
    const int n = L1DIM * L0 / 4;
    if (i < n) {
        float4 v = ((const float4*)W1)[i];
        union { ushort4 u; __hip_bfloat16 h[4]; } pk;
        pk.h[0] = __float2bfloat16(v.x);
        pk.h[1] = __float2bfloat16(v.y);
        pk.h[2] = __float2bfloat16(v.z);
        pk.h[3] = __float2bfloat16(v.w);
        ((ushort4*)W1b)[i] = pk.u;
    }
}

// h1[b]      = relu(BASE[c] + SA[d1] + SB[d2])  (x1)
// h1[4096+b] = relu(BASE[c] + SA[d2] + SB[d1])  (x2)
__global__ __launch_bounds__(256) void build_h_kernel(const int* __restrict__ dp,
                                                      const int* __restrict__ cl,
                                                      const float* __restrict__ SA,
                                                      const float* __restrict__ SB,
                                                      const float* __restrict__ BASE,
                                                      __hip_bfloat16* __restrict__ h1) {
    int b = blockIdx.x;
    int d1 = dp[2 * b], d2 = dp[2 * b + 1], c = cl[b];
    const float* bs = BASE + (size_t)c * L0;
    const float* a1 = SA + (size_t)d1 * L0;
    const float* a2 = SA + (size_t)d2 * L0;
    const float* s1 = SB + (size_t)d1 * L0;
    const float* s2 = SB + (size_t)d2 * L0;
    for (int ch = threadIdx.x * 4; ch < L0; ch += 1024) {
        float4 vb = *(const float4*)(bs + ch);
        float4 va1 = *(const float4*)(a1 + ch);
        float4 va2 = *(const float4*)(a2 + ch);
        float4 vs1 = *(const float4*)(s1 + ch);
        float4 vs2 = *(const float4*)(s2 + ch);
        union { ushort4 u; __hip_bfloat16 h[4]; } p1, p2;
        const float* fb = (const float*)&vb;
        const float* fa1 = (const float*)&va1;
        const float* fa2 = (const float*)&va2;
        const float* fs1 = (const float*)&vs1;
        const float* fs2 = (const float*)&vs2;
#pragma unroll
        for (int j = 0; j < 4; ++j) {
            float z1 = fb[j] + fa1[j] + fs2[j];
            float z2 = fb[j] + fa2[j] + fs1[j];
            p1.h[j] = __float2bfloat16(fmaxf(z1, 0.f));
            p2.h[j] = __float2bfloat16(fmaxf(z2, 0.f));
        }
        *(ushort4*)((__hip_bfloat16*)h1 + (size_t)b * L0 + ch) = p1.u;
        *(ushort4*)((__hip_bfloat16*)h1 + (size_t)(BATCH + b) * L0 + ch) = p2.u;
    }
}

// out[i] = b2 (init for fused atomic layer-2)
__global__ void init_out_kernel(float* __restrict__ out, const float* __restrict__ b2, int n) {
    int i = blockIdx.x * 256 + threadIdx.x;
    if (i < n) out[i] = b2[0];
}

// Fused layers 1+2: C = relu(A @ W1b^T + b1); out += C @ W2  (atomic per row)
// BKK=64, XOR-swizzled LDS (pre-swizzled global source col), XCD block swizzle.
#define BM 128
#define BN 128
#define BK2 64
__global__ __launch_bounds__(256) void gemm_kernel(const __hip_bfloat16* __restrict__ A,
                                                   const __hip_bfloat16* __restrict__ B,
                                                   const float* __restrict__ bias,
                                                   const float* __restrict__ W2,
                                                   float* __restrict__ out,
                                                   int M, int N, int K) {
    __shared__ __hip_bfloat16 As[BM * BK2];
    __shared__ __hip_bfloat16 Bs[BN * BK2];
    int t = threadIdx.x;
    int bid = blockIdx.x;          // 512 blocks
    // XCD swizzle: xcd = bid&7 owns row-strips [xcd*8, xcd*8+8)
    int xcd = bid & 7, ii2 = bid >> 3;       // ii2: 0..63
    int by = xcd * 8 + (ii2 >> 3);           // 0..63
    int bx = ii2 & 7;                        // 0..7
    int brow = by * BM, bcol = bx * BN;
    int w = t >> 6, l = t & 63;
    int wr = w >> 1, wc = w & 1;
    f32x4 acc[4][4] = {};
    int row = l & 15, ko = (l >> 4) * 8;
    int swz = (row & 7) * 8;
    for (int k0 = 0; k0 < K; k0 += BK2) {
#pragma unroll
        for (int i = 0; i < 4; ++i) {
            int idx = i * 256 + t;              // 0..1023
            int r = idx >> 3;
            int cb = ((idx & 7) ^ (r & 7)) * 8; // pre-swizzled source col
            __builtin_amdgcn_global_load_lds(
                (const __attribute__((address_space(1))) void*)(A + (size_t)(brow + r) * K + k0 + cb),
                (__attribute__((address_space(3))) void*)(&As[idx * 8]), 16, 0, 0);
            __builtin_amdgcn_global_load_lds(
                (const __attribute__((address_space(1))) void*)(B + (size_t)(bcol + r) * K + k0 + cb),
                (__attribute__((address_space(3))) void*)(&Bs[idx * 8]), 16, 0, 0);
        }
        __syncthreads();
#pragma unroll
        for (int ks = 0; ks < 2; ++ks) {
            int col = (ks * 32 + ko) ^ swz;
            s16x8 af[4], bfr[4];
#pragma unroll
            for (int m = 0; m < 4; ++m)
                af[m] = *(const s16x8*)(&As[(wr * 64 + m * 16 + row) * BK2 + col]);
#pragma unroll
            for (int n = 0; n < 4; ++n)
                bfr[n] = *(const s16x8*)(&Bs[(wc * 64 + n * 16 + row) * BK2 + col]);
#pragma unroll
            for (int m = 0; m < 4; ++m)
#pragma unroll
                for (int n = 0; n < 4; ++n)
                    acc[m][n] = __builtin_amdgcn_mfma_f32_16x16x32_bf16(af[m], bfr[n], acc[m][n], 0, 0, 0);
        }
        __syncthreads();
    }
    // fused epilogue: s_row = sum_cols relu(acc + b1[col]) * W2[col]
    int cr = (l >> 4) * 4;
    int cc = l & 15;
#pragma unroll
    for (int m = 0; m < 4; ++m) {
        float s[4] = {0.f, 0.f, 0.f, 0.f};
#pragma unroll
        for (int n = 0; n < 4; ++n) {
            int gcol = bcol + wc * 64 + n * 16 + cc;
            float bv = bias[gcol];
            float wv = W2[gcol];
#pragma unroll
            for (int j = 0; j < 4; ++j) {
                float v = fmaxf(acc[m][n][j] + bv, 0.f);
                s[j] += v * wv;
            }
        }
#pragma unroll
        for (int mask = 1; mask < 16; mask <<= 1) {
#pragma unroll
            for (int j = 0; j < 4; ++j) s[j] += __shfl_xor(s[j], mask);
        }
        if (cc == 0) {
            int grow = brow + wr * 64 + m * 16 + cr;
#pragma unroll
            for (int j = 0; j < 4; ++j) atomicAdd(&out[grow + j], s[j]);
        }
    }
}

extern "C" void kernel_launch(void* const* d_in, const int* in_sizes, int n_in,
                              void* d_out, int out_size, void* d_ws, size_t ws_size,
                              hipStream_t stream) {
    const int* drug_pairs = (const int*)d_in[0];
    const int* cell_lines = (const int*)d_in[1];
    const int* dpi_drug = (const int*)d_in[2];
    const int* dpi_prot = (const int*)d_in[3];
    const float* W0 = (const float*)d_in[4];
    const float* b0 = (const float*)d_in[5];
    const float* W1 = (const float*)d_in[6];
    const float* b1 = (const float*)d_in[7];
    const float* W2 = (const float*)d_in[8];
    const float* b2 = (const float*)d_in[9];
    float* out = (float*)d_out;

    char* ws = (char*)d_ws;
    size_t off = 0;
    auto alloc = [&](size_t bytes) {
        char* p = ws + off;
        off += (bytes + 255) & ~(size_t)255;
        return p;
    };
    float* SA = (float*)alloc((size_t)NDRUG * L0 * 4);
    float* SB = (float*)alloc((size_t)NDRUG * L0 * 4);
    float* BASE = (float*)alloc((size_t)NCELL * L0 * 4);
    __hip_bfloat16* W1b = (__hip_bfloat16*)alloc((size_t)L1DIM * L0 * 2);
    __hip_bfloat16* h1 = (__hip_bfloat16*)alloc((size_t)2 * BATCH * L0 * 2);
    // contiguous zero region: hist, cnt
    const int ZREG_N = 2 * NDRUG;
    int* zreg = (int*)alloc((size_t)ZREG_N * 4);
    int* hist = zreg;
    int* cnt = zreg + NDRUG;
    int* dptr = (int*)alloc((size_t)(NDRUG + 1) * 4);
    int* dtmp = (int*)alloc((size_t)NEDGE * 4);
    int* dcnt = (int*)alloc((size_t)NDRUG * 4);
    int* wlen = (int*)alloc(8 * 4);
    int* wbase = (int*)alloc(8 * 4);
    int* pref = (int*)alloc((size_t)512 * 8 * 4);
    int* tcnt = (int*)alloc((size_t)512 * 4);
    unsigned short* estream = (unsigned short*)alloc((size_t)64 * (NEDGE + NDRUG + 512) * 2);

    zero_all_kernel<<<(ZREG_N + 255) / 256, 256, 0, stream>>>(zreg, ZREG_N);
    hist_kernel<<<(NEDGE + 255) / 256, 256, 0, stream>>>(dpi_drug, hist);
    scan_kernel<<<1, 256, 0, stream>>>(hist, dptr, NDRUG);
    scatter_kernel<<<(NEDGE + 255) / 256, 256, 0, stream>>>(dpi_drug, dpi_prot, dptr, cnt, dtmp);
    sortdedup_kernel<<<(NDRUG + 255) / 256, 256, 0, stream>>>(dptr, dtmp, dcnt);
    stream_meta_kernel<<<1, 512, 0, stream>>>(dcnt, wlen, wbase, pref, tcnt);
    fill_stream_kernel<<<(NDRUG + 512 + 255) / 256, 256, 0, stream>>>(dptr, dcnt, dtmp, wbase,
                                                                      wlen, pref, tcnt, estream);
    base_kernel<<<(NCELL * L0 + 255) / 256, 256, 0, stream>>>(W0, b0, BASE);
    drug_sum_kernel<<<L0 / 2, 512, 0, stream>>>(W0, estream, wbase, wlen, SA, SB);
    cvtw1_kernel<<<(L1DIM * L0 / 4 + 255) / 256, 256, 0, stream>>>(W1, W1b);
    build_h_kernel<<<BATCH, 256, 0, stream>>>(drug_pairs, cell_lines, SA, SB, BASE, h1);
    init_out_kernel<<<(2 * BATCH + 255) / 256, 256, 0, stream>>>(out, b2, 2 * BATCH);
    gemm_kernel<<<(2 * BATCH / BM) * (L1DIM / BN), 256, 0, stream>>>(h1, W1b, b1, W2, out,
                                                                     2 * BATCH, L1DIM, L0);
}

// Round 12
// 224.473 us; speedup vs baseline: 1.8498x; 1.1780x over previous
//
#include <hip/hip_runtime.h>
#include <hip/hip_bf16.h>
#include <stdint.h>

#define NPROT 19000
#define NDRUG 4000
#define NCELL 16
#define BATCH 4096
#define NEDGE 40000
#define L0 2048
#define L1DIM 1024
#define INDIM 38032
#define HALFDIM 19016
#define WSTN 19008   // protein slots: 19000 + 8 pad (dummy at 19000)
#define DCAP 96      // max deduped proteins per drug (avg 10, Poisson tail << 96)
#define BMWORDS ((NDRUG * NPROT + 31) / 32)   // dedup bitmap words

typedef float f32x4 __attribute__((ext_vector_type(4)));
typedef short s16x8 __attribute__((ext_vector_type(8)));

__global__ void zero_all_kernel(int* __restrict__ p, int n) {
    int i = blockIdx.x * 256 + threadIdx.x;
    if (i < n) p[i] = 0;
}

// dedup via bitmap (reference .set(1.0) semantics; order within drug irrelevant)
// first setter of bit (d,p) appends p to dlist[d*DCAP + cnt[d]++]
__global__ void scatter_dedup_kernel(const int* __restrict__ drug, const int* __restrict__ prot,
                                     unsigned* __restrict__ bitmap, int* __restrict__ cnt,
                                     unsigned short* __restrict__ dlist) {
    int e = blockIdx.x * 256 + threadIdx.x;
    if (e < NEDGE) {
        int d = drug[e], p = prot[e];
        unsigned idx = (unsigned)d * NPROT + p;
        unsigned bit = 1u << (idx & 31u);
        unsigned old = atomicOr(&bitmap[idx >> 5], bit);
        if (!(old & bit)) {
            int pos = atomicAdd(&cnt[d], 1);
            if (pos < DCAP) dlist[d * DCAP + pos] = (unsigned short)p;
        }
    }
}

// per-slot (512 threads) prefix of entry counts over the 8 owned drugs;
// wlen[w] = max over 64 lanes of total; wbase = running base
__global__ __launch_bounds__(512) void stream_meta_kernel(const int* __restrict__ cnt,
                                                          int* __restrict__ wlen,
                                                          int* __restrict__ wbase,
                                                          int* __restrict__ pref,
                                                          int* __restrict__ tcnt) {
    __shared__ int wl[8];
    int t = threadIdx.x;
    if (t < 8) wl[t] = 0;
    __syncthreads();
    int c = 0;
#pragma unroll
    for (int k = 0; k < 8; ++k) {
        int d = t + (k << 9);
        pref[t * 8 + k] = c;
        if (d < NDRUG) c += max(min(cnt[d], DCAP), 1);
    }
    tcnt[t] = c;
    atomicMax(&wl[t >> 6], c);
    __syncthreads();
    if (t == 0) {
        int run = 0;
        for (int w = 0; w < 8; ++w) {
            wlen[w] = wl[w];
            wbase[w] = run;
            run += wl[w] * 64;
        }
    }
}

// drug-parallel fill of the wave-interleaved u16 stream.
// entry = p | (last<<15); slot t's i-th entry at wbase[t>>6] + (t&63) + i*64.
__global__ __launch_bounds__(256) void fill_stream_kernel(const int* __restrict__ cnt,
                                                          const unsigned short* __restrict__ dlist,
                                                          const int* __restrict__ wbase,
                                                          const int* __restrict__ wlen,
                                                          const int* __restrict__ pref,
                                                          const int* __restrict__ tcnt,
                                                          unsigned short* __restrict__ estream) {
    int g = blockIdx.x * 256 + threadIdx.x;
    if (g < NDRUG) {
        int d = g;
        int t = d & 511, k = d >> 9;
        int base = wbase[t >> 6] + (t & 63);
        int idx = pref[t * 8 + k];
        int n = min(cnt[d], DCAP);
        if (n == 0) {
            estream[base + idx * 64] = (unsigned short)(19000 | 0x8000);
        } else {
            for (int i = 0; i < n; ++i) {
                unsigned short e = dlist[d * DCAP + i];
                if (i == n - 1) e |= 0x8000;
                estream[base + (idx + i) * 64] = e;
            }
        }
    } else if (g < NDRUG + 512) {
        int t = g - NDRUG;
        int base = wbase[t >> 6] + (t & 63);
        int wl = wlen[t >> 6];
        for (int idx = tcnt[t]; idx < wl; ++idx)
            estream[base + idx * 64] = (unsigned short)19000;
    }
}

// BASE[c][ch] = b0[ch] + W0[ch, 19000+c] + W0[ch, 38016+c]
__global__ void base_kernel(const float* __restrict__ W0, const float* __restrict__ b0,
                            float* __restrict__ BASE) {
    int i = blockIdx.x * 256 + threadIdx.x;
    if (i < NCELL * L0) {
        int c = i >> 11, ch = i & 2047;
        const float* wr = W0 + (size_t)ch * INDIM;
        BASE[(size_t)c * L0 + ch] = b0[ch] + wr[NPROT + c] + wr[HALFDIM + NPROT + c];
    }
}

// RNE f32->bf16 pair pack: low16 = a, high16 = b
__device__ inline unsigned bfpair(float a, float b) {
    unsigned ua = __float_as_uint(a), ub = __float_as_uint(b);
    ua += 0x7fffu + ((ua >> 16) & 1u);
    ub += 0x7fffu + ((ub >> 16) & 1u);
    return (ua >> 16) | (ub & 0xffff0000u);
}
__device__ inline float bflo(unsigned w) { return __uint_as_float(w << 16); }
__device__ inline float bfhi(unsigned w) { return __uint_as_float(w & 0xffff0000u); }

// Register-accumulator drug sum, 4 channels/block as 2 packed-bf16 dwords.
// Output SA/SB in packed bf16 (halves write traffic).
__global__ __launch_bounds__(512) void drug_sum_kernel(const float* __restrict__ W0,
                                                       const unsigned short* __restrict__ estream,
                                                       const int* __restrict__ wbase,
                                                       const int* __restrict__ wlen,
                                                       __hip_bfloat16* __restrict__ SAb,
                                                       __hip_bfloat16* __restrict__ SBb) {
    __shared__ uint2 wst[WSTN];  // 152064 B
    int t = threadIdx.x;
    int bid = blockIdx.x;        // 1024 blocks
    int j = bid & 7;
    int k2 = bid >> 3;           // 0..127
    int ch4 = k2 & 3;
    int ghi = k2 >> 2;           // 0..31
    int group = j + 8 * ghi;     // 0..255
    int hb = group >> 7;
    int line = group & 127;
    int ch0 = line * 16 + ch4 * 4;
    size_t colbase = (size_t)hb * HALFDIM;

    // prefetch first estream batch (independent of wst) to hide cold latency
    int wv = t >> 6;
    int base = wbase[wv] + (t & 63);
    int wl = wlen[wv];
    int nfull = wl >> 3, rem = wl & 7;
    unsigned e[8];
    if (nfull > 0) {
#pragma unroll
        for (int k = 0; k < 8; ++k) e[k] = estream[base + k * 64];
        base += 512;
    }

    const float* sA = W0 + (size_t)(ch0 + 0) * INDIM + colbase;
    const float* sB = W0 + (size_t)(ch0 + 1) * INDIM + colbase;
    const float* sC = W0 + (size_t)(ch0 + 2) * INDIM + colbase;
    const float* sD = W0 + (size_t)(ch0 + 3) * INDIM + colbase;
    for (int i = t * 4; i < 19000; i += 2048) {
        float4 a = *(const float4*)(sA + i);
        float4 b = *(const float4*)(sB + i);
        float4 c = *(const float4*)(sC + i);
        float4 d = *(const float4*)(sD + i);
        uint4 q0, q1;
        q0.x = bfpair(a.x, b.x); q0.y = bfpair(c.x, d.x);
        q0.z = bfpair(a.y, b.y); q0.w = bfpair(c.y, d.y);
        q1.x = bfpair(a.z, b.z); q1.y = bfpair(c.z, d.z);
        q1.z = bfpair(a.w, b.w); q1.w = bfpair(c.w, d.w);
        *(uint4*)&wst[i] = q0;
        *(uint4*)&wst[i + 2] = q1;
    }
    if (t < 8) { wst[19000 + t].x = 0u; wst[19000 + t].y = 0u; }
    __syncthreads();

    float x0 = 0.f, x1 = 0.f, x2 = 0.f, x3 = 0.f;
    int kk = 0;
    __hip_bfloat16* dst = (hb ? SBb : SAb) + ch0;

    auto process = [&](const unsigned* ev) {
#pragma unroll
        for (int k = 0; k < 8; ++k) {
            uint2 w = wst[ev[k] & 0x7fffu];
            x0 += bflo(w.x);
            x1 += bfhi(w.x);
            x2 += bflo(w.y);
            x3 += bfhi(w.y);
            if (ev[k] & 0x8000u) {
                uint2 v;
                v.x = bfpair(x0, x1);
                v.y = bfpair(x2, x3);
                *(uint2*)&dst[(size_t)(t + (kk << 9)) * L0] = v;
                ++kk; x0 = 0.f; x1 = 0.f; x2 = 0.f; x3 = 0.f;
            }
        }
    };

    if (nfull > 0) {
        for (int it = 1; it < nfull; ++it) {
            unsigned f[8];
#pragma unroll
            for (int k = 0; k < 8; ++k) f[k] = estream[base + k * 64];
            base += 512;
            process(e);
#pragma unroll
            for (int k = 0; k < 8; ++k) e[k] = f[k];
        }
        process(e);
    }
    for (int k = 0; k < rem; ++k) {
        unsigned ev = estream[base + k * 64];
        uint2 w = wst[ev & 0x7fffu];
        x0 += bflo(w.x);
        x1 += bfhi(w.x);
        x2 += bflo(w.y);
        x3 += bfhi(w.y);
        if (ev & 0x8000u) {
            uint2 v;
            v.x = bfpair(x0, x1);
            v.y = bfpair(x2, x3);
            *(uint2*)&dst[(size_t)(t + (kk << 9)) * L0] = v;
            ++kk; x0 = 0.f; x1 = 0.f; x2 = 0.f; x3 = 0.f;
        }
    }
}

__global__ void cvtw1_kernel(const float* __restrict__ W1, __hip_bfloat16* __restrict__ W1b) {
    int i = blockIdx.x * 256 + threadIdx.x;  // one float4 each
    const int n = L1DIM * L0 / 4;
    if (i < n) {
        float4 v = ((const float4*)W1)[i];
        uint2 q;
        q.x = bfpair(v.x, v.y);
        q.y = bfpair(v.z, v.w);
        ((uint2*)W1b)[i] = q;
    }
}

// h1[b]      = relu(BASE[c] + SA[d1] + SB[d2])  (x1)
// h1[4096+b] = relu(BASE[c] + SA[d2] + SB[d1])  (x2)
// one iteration: thread owns 8 channels (256*8 = 2048)
__global__ __launch_bounds__(256) void build_h_kernel(const int* __restrict__ dp,
                                                      const int* __restrict__ cl,
                                                      const __hip_bfloat16* __restrict__ SAb,
                                                      const __hip_bfloat16* __restrict__ SBb,
                                                      const float* __restrict__ BASE,
                                                      __hip_bfloat16* __restrict__ h1) {
    int b = blockIdx.x;
    int d1 = dp[2 * b], d2 = dp[2 * b + 1], c = cl[b];
    int ch = threadIdx.x * 8;
    const float* bs = BASE + (size_t)c * L0 + ch;
    uint4 ua1 = *(const uint4*)(SAb + (size_t)d1 * L0 + ch);
    uint4 ua2 = *(const uint4*)(SAb + (size_t)d2 * L0 + ch);
    uint4 us1 = *(const uint4*)(SBb + (size_t)d1 * L0 + ch);
    uint4 us2 = *(const uint4*)(SBb + (size_t)d2 * L0 + ch);
    float4 vb0 = *(const float4*)(bs);
    float4 vb1 = *(const float4*)(bs + 4);
    float bsv[8] = {vb0.x, vb0.y, vb0.z, vb0.w, vb1.x, vb1.y, vb1.z, vb1.w};
    unsigned a1w[4] = {ua1.x, ua1.y, ua1.z, ua1.w};
    unsigned a2w[4] = {ua2.x, ua2.y, ua2.z, ua2.w};
    unsigned s1w[4] = {us1.x, us1.y, us1.z, us1.w};
    unsigned s2w[4] = {us2.x, us2.y, us2.z, us2.w};
    float z1[8], z2[8];
#pragma unroll
    for (int k = 0; k < 4; ++k) {
        z1[2 * k]     = fmaxf(bsv[2 * k]     + bflo(a1w[k]) + bflo(s2w[k]), 0.f);
        z1[2 * k + 1] = fmaxf(bsv[2 * k + 1] + bfhi(a1w[k]) + bfhi(s2w[k]), 0.f);
        z2[2 * k]     = fmaxf(bsv[2 * k]     + bflo(a2w[k]) + bflo(s1w[k]), 0.f);
        z2[2 * k + 1] = fmaxf(bsv[2 * k + 1] + bfhi(a2w[k]) + bfhi(s1w[k]), 0.f);
    }
    uint4 o1, o2;
    o1.x = bfpair(z1[0], z1[1]); o1.y = bfpair(z1[2], z1[3]);
    o1.z = bfpair(z1[4], z1[5]); o1.w = bfpair(z1[6], z1[7]);
    o2.x = bfpair(z2[0], z2[1]); o2.y = bfpair(z2[2], z2[3]);
    o2.z = bfpair(z2[4], z2[5]); o2.w = bfpair(z2[6], z2[7]);
    *(uint4*)((__hip_bfloat16*)h1 + (size_t)b * L0 + ch) = o1;
    *(uint4*)((__hip_bfloat16*)h1 + (size_t)(BATCH + b) * L0 + ch) = o2;
}

// out[i] = b2 (init for fused atomic layer-2)
__global__ void init_out_kernel(float* __restrict__ out, const float* __restrict__ b2, int n) {
    int i = blockIdx.x * 256 + threadIdx.x;
    if (i < n) out[i] = b2[0];
}

// Fused layers 1+2: C = relu(A @ W1b^T + b1); out += C @ W2  (atomic per row)
// BKK=64, XOR-swizzled LDS (pre-swizzled global source col), XCD block swizzle.
#define BM 128
#define BN 128
#define BK2 64
__global__ __launch_bounds__(256) void gemm_kernel(const __hip_bfloat16* __restrict__ A,
                                                   const __hip_bfloat16* __restrict__ B,
                                                   const float* __restrict__ bias,
                                                   const float* __restrict__ W2,
                                                   float* __restrict__ out,
                                                   int M, int N, int K) {
    __shared__ __hip_bfloat16 As[BM * BK2];
    __shared__ __hip_bfloat16 Bs[BN * BK2];
    int t = threadIdx.x;
    int bid = blockIdx.x;          // 512 blocks
    int xcd = bid & 7, ii2 = bid >> 3;       // ii2: 0..63
    int by = xcd * 8 + (ii2 >> 3);           // 0..63
    int bx = ii2 & 7;                        // 0..7
    int brow = by * BM, bcol = bx * BN;
    int w = t >> 6, l = t & 63;
    int wr = w >> 1, wc = w & 1;
    f32x4 acc[4][4] = {};
    int row = l & 15, ko = (l >> 4) * 8;
    int swz = (row & 7) * 8;
    for (int k0 = 0; k0 < K; k0 += BK2) {
#pragma unroll
        for (int i = 0; i < 4; ++i) {
            int idx = i * 256 + t;              // 0..1023
            int r = idx >> 3;
            int cb = ((idx & 7) ^ (r & 7)) * 8; // pre-swizzled source col
            __builtin_amdgcn_global_load_lds(
                (const __attribute__((address_space(1))) void*)(A + (size_t)(brow + r) * K + k0 + cb),
                (__attribute__((address_space(3))) void*)(&As[idx * 8]), 16, 0, 0);
            __builtin_amdgcn_global_load_lds(
                (const __attribute__((address_space(1))) void*)(B + (size_t)(bcol + r) * K + k0 + cb),
                (__attribute__((address_space(3))) void*)(&Bs[idx * 8]), 16, 0, 0);
        }
        __syncthreads();
#pragma unroll
        for (int ks = 0; ks < 2; ++ks) {
            int col = (ks * 32 + ko) ^ swz;
            s16x8 af[4], bfr[4];
#pragma unroll
            for (int m = 0; m < 4; ++m)
                af[m] = *(const s16x8*)(&As[(wr * 64 + m * 16 + row) * BK2 + col]);
#pragma unroll
            for (int n = 0; n < 4; ++n)
                bfr[n] = *(const s16x8*)(&Bs[(wc * 64 + n * 16 + row) * BK2 + col]);
#pragma unroll
            for (int m = 0; m < 4; ++m)
#pragma unroll
                for (int n = 0; n < 4; ++n)
                    acc[m][n] = __builtin_amdgcn_mfma_f32_16x16x32_bf16(af[m], bfr[n], acc[m][n], 0, 0, 0);
        }
        __syncthreads();
    }
    // fused epilogue: s_row = sum_cols relu(acc + b1[col]) * W2[col]
    int cr = (l >> 4) * 4;
    int cc = l & 15;
#pragma unroll
    for (int m = 0; m < 4; ++m) {
        float s[4] = {0.f, 0.f, 0.f, 0.f};
#pragma unroll
        for (int n = 0; n < 4; ++n) {
            int gcol = bcol + wc * 64 + n * 16 + cc;
            float bv = bias[gcol];
            float wv = W2[gcol];
#pragma unroll
            for (int j = 0; j < 4; ++j) {
                float v = fmaxf(acc[m][n][j] + bv, 0.f);
                s[j] += v * wv;
            }
        }
#pragma unroll
        for (int mask = 1; mask < 16; mask <<= 1) {
#pragma unroll
            for (int j = 0; j < 4; ++j) s[j] += __shfl_xor(s[j], mask);
        }
        if (cc == 0) {
            int grow = brow + wr * 64 + m * 16 + cr;
#pragma unroll
            for (int j = 0; j < 4; ++j) atomicAdd(&out[grow + j], s[j]);
        }
    }
}

extern "C" void kernel_launch(void* const* d_in, const int* in_sizes, int n_in,
                              void* d_out, int out_size, void* d_ws, size_t ws_size,
                              hipStream_t stream) {
    const int* drug_pairs = (const int*)d_in[0];
    const int* cell_lines = (const int*)d_in[1];
    const int* dpi_drug = (const int*)d_in[2];
    const int* dpi_prot = (const int*)d_in[3];
    const float* W0 = (const float*)d_in[4];
    const float* b0 = (const float*)d_in[5];
    const float* W1 = (const float*)d_in[6];
    const float* b1 = (const float*)d_in[7];
    const float* W2 = (const float*)d_in[8];
    const float* b2 = (const float*)d_in[9];
    float* out = (float*)d_out;

    char* ws = (char*)d_ws;
    size_t off = 0;
    auto alloc = [&](size_t bytes) {
        char* p = ws + off;
        off += (bytes + 255) & ~(size_t)255;
        return p;
    };
    __hip_bfloat16* SAb = (__hip_bfloat16*)alloc((size_t)NDRUG * L0 * 2);
    __hip_bfloat16* SBb = (__hip_bfloat16*)alloc((size_t)NDRUG * L0 * 2);
    float* BASE = (float*)alloc((size_t)NCELL * L0 * 4);
    __hip_bfloat16* W1b = (__hip_bfloat16*)alloc((size_t)L1DIM * L0 * 2);
    __hip_bfloat16* h1 = (__hip_bfloat16*)alloc((size_t)2 * BATCH * L0 * 2);
    // contiguous zero region: bitmap + cnt
    const int ZREG_N = BMWORDS + NDRUG;
    int* zreg = (int*)alloc((size_t)ZREG_N * 4);
    unsigned* bitmap = (unsigned*)zreg;
    int* cnt = zreg + BMWORDS;
    unsigned short* dlist = (unsigned short*)alloc((size_t)NDRUG * DCAP * 2);
    int* wlen = (int*)alloc(8 * 4);
    int* wbase = (int*)alloc(8 * 4);
    int* pref = (int*)alloc((size_t)512 * 8 * 4);
    int* tcnt = (int*)alloc((size_t)512 * 4);
    unsigned short* estream = (unsigned short*)alloc((size_t)64 * (NEDGE + NDRUG + 512) * 2);

    zero_all_kernel<<<(ZREG_N + 255) / 256, 256, 0, stream>>>(zreg, ZREG_N);
    scatter_dedup_kernel<<<(NEDGE + 255) / 256, 256, 0, stream>>>(dpi_drug, dpi_prot,
                                                                  bitmap, cnt, dlist);
    stream_meta_kernel<<<1, 512, 0, stream>>>(cnt, wlen, wbase, pref, tcnt);
    fill_stream_kernel<<<(NDRUG + 512 + 255) / 256, 256, 0, stream>>>(cnt, dlist, wbase,
                                                                      wlen, pref, tcnt, estream);
    base_kernel<<<(NCELL * L0 + 255) / 256, 256, 0, stream>>>(W0, b0, BASE);
    drug_sum_kernel<<<L0 / 2, 512, 0, stream>>>(W0, estream, wbase, wlen, SAb, SBb);
    cvtw1_kernel<<<(L1DIM * L0 / 4 + 255) / 256, 256, 0, stream>>>(W1, W1b);
    build_h_kernel<<<BATCH, 256, 0, stream>>>(drug_pairs, cell_lines, SAb, SBb, BASE, h1);
    init_out_kernel<<<(2 * BATCH + 255) / 256, 256, 0, stream>>>(out, b2, 2 * BATCH);
    gemm_kernel<<<(2 * BATCH / BM) * (L1DIM / BN), 256, 0, stream>>>(h1, W1b, b1, W2, out,
                                                                     2 * BATCH, L1DIM, L0);
}